// Round 9
// baseline (1072.953 us; speedup 1.0000x reference)
//
#include <hip/hip_runtime.h>
#include <hip/hip_bf16.h>
#include <stdint.h>

typedef short  bf16x8 __attribute__((ext_vector_type(8)));
typedef short  bf16x4 __attribute__((ext_vector_type(4)));
typedef float  f32x4  __attribute__((ext_vector_type(4)));
typedef unsigned short u16x8 __attribute__((ext_vector_type(8)));
typedef unsigned short u16x4 __attribute__((ext_vector_type(4)));
typedef float  fx4    __attribute__((ext_vector_type(4)));

#define LDSP(p) ((__attribute__((address_space(3))) void*)(p))
#define GLBP(p) ((const __attribute__((address_space(1))) void*)(p))

__device__ __forceinline__ unsigned short f2bf(float x) {
    union { float f; unsigned u; } v; v.f = x;
    unsigned r = (v.u + 0x7FFFu + ((v.u >> 16) & 1u)) >> 16;
    return (unsigned short)r;
}
// native path: compiler emits v_cvt_pk_bf16_f32 for paired casts
__device__ __forceinline__ unsigned short fcvt(float x) {
    __hip_bfloat16 h = __float2bfloat16(x);
    return __builtin_bit_cast(unsigned short, h);
}

// ---------------- all converts in one launch: y 0-4 plain, y 5-6 row-pad ----
__global__ __launch_bounds__(256)
void cvt_all(const float* __restrict__ s0, unsigned short* __restrict__ d0, long n0,
             const float* __restrict__ s1, unsigned short* __restrict__ d1, long n1,
             const float* __restrict__ s2, unsigned short* __restrict__ d2, long n2,
             const float* __restrict__ s3, unsigned short* __restrict__ d3, long n3,
             const float* __restrict__ s4, unsigned short* __restrict__ d4, long n4,
             const float* __restrict__ s5, unsigned short* __restrict__ d5,
             const float* __restrict__ s6, unsigned short* __restrict__ d6)
{
    const int slice = blockIdx.y;
    long i = ((long)blockIdx.x * 256 + threadIdx.x) * 8;
    u16x8 o;
    if (slice < 5) {
        const float* s; unsigned short* d; long n;
        switch (slice) {
            case 0: s = s0; d = d0; n = n0; break;
            case 1: s = s1; d = d1; n = n1; break;
            case 2: s = s2; d = d2; n = n2; break;
            case 3: s = s3; d = d3; n = n3; break;
            default: s = s4; d = d4; n = n4; break;
        }
        if (i + 8 > n) return;
        fx4 a = *(const fx4*)(s + i);
        fx4 b = *(const fx4*)(s + i + 4);
        o[0]=f2bf(a[0]); o[1]=f2bf(a[1]); o[2]=f2bf(a[2]); o[3]=f2bf(a[3]);
        o[4]=f2bf(b[0]); o[5]=f2bf(b[1]); o[6]=f2bf(b[2]); o[7]=f2bf(b[3]);
        *(u16x8*)(d + i) = o;
    } else {
        const float* src = (slice == 5) ? s5 : s6;
        unsigned short* dst = (slice == 5) ? d5 : d6;
        int row = (int)(i >> 12);
        if (row < 1000) {
            long si = (long)row * 4096 + (i & 4095);
            fx4 a = *(const fx4*)(src + si);
            fx4 b = *(const fx4*)(src + si + 4);
            o[0]=f2bf(a[0]); o[1]=f2bf(a[1]); o[2]=f2bf(a[2]); o[3]=f2bf(a[3]);
            o[4]=f2bf(b[0]); o[5]=f2bf(b[1]); o[6]=f2bf(b[2]); o[7]=f2bf(b[3]);
        } else {
            #pragma unroll
            for (int j = 0; j < 8; ++j) o[j] = 0;
        }
        *(u16x8*)(dst + i) = o;
    }
}

// ---------------- fused Q + K|V projections, one 768-block launch ----------
__global__ __launch_bounds__(256)
void proj_fused(const unsigned short* __restrict__ tgt, const unsigned short* __restrict__ wq,
                const unsigned short* __restrict__ src, const unsigned short* __restrict__ val,
                const unsigned short* __restrict__ wkv,
                const float* __restrict__ bq, unsigned short* __restrict__ Qb,
                float* __restrict__ Pk, float* __restrict__ Pv)
{
    __shared__ unsigned short Alds[128 * 32];
    __shared__ unsigned short Blds[128 * 32];
    const int bid = blockIdx.x;
    const int tid = threadIdx.x;
    const int l = tid & 63, w = tid >> 6;
    const int wr = w >> 1, wc = w & 1;
    const int g = l >> 4, lc = l & 15;

    const unsigned short *A, *B;
    long tm, tn, lda;
    int kbeg;
    if (bid < 256) {
        tm = (long)(bid >> 3) * 128; tn = (long)(bid & 7) * 128;
        A = tgt; B = wq; lda = 1024; kbeg = 0;
    } else {
        const int idx = bid - 256;           // 0..511
        const int tnq = idx >> 5;            // 0..15 col tile
        const int kz  = (idx >> 3) & 3;      // 0..3
        tm = (long)(idx & 7) * 128; tn = (long)tnq * 128;
        A = (tnq < 8) ? src : val; B = wkv; lda = 4096; kbeg = kz * 1024;
    }

    f32x4 acc[4][4] = {};

    const int r0 = tid >> 2,           c0 = (tid & 3) * 8;
    const int r1 = (tid + 256) >> 2,   c1 = ((tid + 256) & 3) * 8;
    const unsigned short* a0 = A + (tm + r0) * lda + c0;
    const unsigned short* a1 = A + (tm + r1) * lda + c1;
    const unsigned short* b0 = B + (tn + r0) * lda + c0;
    const unsigned short* b1 = B + (tn + r1) * lda + c1;

    const int kend = kbeg + 1024;
    for (int k0 = kbeg; k0 < kend; k0 += 32) {
        __builtin_amdgcn_global_load_lds(GLBP(a0 + k0), LDSP(Alds + tid * 8),         16, 0, 0);
        __builtin_amdgcn_global_load_lds(GLBP(a1 + k0), LDSP(Alds + (tid + 256) * 8), 16, 0, 0);
        __builtin_amdgcn_global_load_lds(GLBP(b0 + k0), LDSP(Blds + tid * 8),         16, 0, 0);
        __builtin_amdgcn_global_load_lds(GLBP(b1 + k0), LDSP(Blds + (tid + 256) * 8), 16, 0, 0);
        __syncthreads();
        bf16x8 af[4], bfv[4];
        #pragma unroll
        for (int m = 0; m < 4; ++m)
            af[m] = *(const bf16x8*)&Alds[(wr * 64 + m * 16 + lc) * 32 + g * 8];
        #pragma unroll
        for (int n = 0; n < 4; ++n)
            bfv[n] = *(const bf16x8*)&Blds[(wc * 64 + n * 16 + lc) * 32 + g * 8];
        #pragma unroll
        for (int m = 0; m < 4; ++m)
            #pragma unroll
            for (int n = 0; n < 4; ++n)
                acc[m][n] = __builtin_amdgcn_mfma_f32_16x16x32_bf16(af[m], bfv[n], acc[m][n], 0, 0, 0);
        __syncthreads();
    }

    if (bid < 256) {
        const float qscale = 0.08838834764831845f * 1.4426950408889634f;  // 1/sqrt(128)*log2e
        #pragma unroll
        for (int n = 0; n < 4; ++n) {
            const long col = tn + wc * 64 + n * 16 + lc;
            const float bv = bq[col];
            #pragma unroll
            for (int m = 0; m < 4; ++m)
                #pragma unroll
                for (int r = 0; r < 4; ++r) {
                    const long row = tm + wr * 64 + m * 16 + g * 4 + r;
                    Qb[row * 1024 + col] = f2bf((acc[m][n][r] + bv) * qscale);
                }
        }
    } else {
        const int kz = ((bid - 256) >> 3) & 3;
        const long zoff = (long)kz << 20;
        #pragma unroll
        for (int n = 0; n < 4; ++n) {
            const long col = tn + wc * 64 + n * 16 + lc;
            #pragma unroll
            for (int m = 0; m < 4; ++m)
                #pragma unroll
                for (int r = 0; r < 4; ++r) {
                    const long row = tm + wr * 64 + m * 16 + g * 4 + r;
                    if (col < 1024) Pk[zoff + row * 1024 + col] = acc[m][n][r];
                    else            Pv[zoff + (col - 1024) * 1024 + row] = acc[m][n][r];
                }
        }
    }
}

// sum 4 split-K partials + bias -> bf16.  y=0: K [s][e] bias on col; y=1: VT [e][s] bias on row.
__global__ __launch_bounds__(256)
void combine4(const float* __restrict__ Pk, const float* __restrict__ Pv,
              const float* __restrict__ bk, const float* __restrict__ bv,
              unsigned short* __restrict__ Kb, unsigned short* __restrict__ VTb)
{
    const int half = blockIdx.y;
    const float* P = half ? Pv : Pk;
    long i = ((long)blockIdx.x * 256 + threadIdx.x) * 4;   // over 1M elems
    fx4 a = *(const fx4*)(P + i);
    fx4 b = *(const fx4*)(P + (1L << 20) + i);
    fx4 c = *(const fx4*)(P + (2L << 20) + i);
    fx4 d = *(const fx4*)(P + (3L << 20) + i);
    const int row = (int)(i >> 10), col = (int)(i & 1023);
    float bb0, bb1, bb2, bb3;
    if (half) { float x = bv[row]; bb0 = bb1 = bb2 = bb3 = x; }
    else      { bb0 = bk[col]; bb1 = bk[col + 1]; bb2 = bk[col + 2]; bb3 = bk[col + 3]; }
    u16x4 o;
    o[0] = f2bf((a[0] + b[0]) + (c[0] + d[0]) + bb0);
    o[1] = f2bf((a[1] + b[1]) + (c[1] + d[1]) + bb1);
    o[2] = f2bf((a[2] + b[2]) + (c[2] + d[2]) + bb2);
    o[3] = f2bf((a[3] + b[3]) + (c[3] + d[3]) + bb3);
    *(u16x4*)((half ? VTb : Kb) + i) = o;
}

// ---------------- flash attention with K register double-buffer ------------
#define ATTN_TILE(T, KC, KN)                                                          \
    do {                                                                              \
        bf16x4 v0[8], v1[8];                                                          \
        _Pragma("unroll")                                                             \
        for (int es = 0; es < 8; ++es) {                                              \
            const unsigned short* vp = Vp + (long)es * 16384 + (T) * 32;              \
            v0[es] = *(const bf16x4*)vp;                                              \
            v1[es] = *(const bf16x4*)(vp + 16);                                       \
        }                                                                             \
        if ((T) < 31) {                                                               \
            const unsigned short* kp = Kp + (long)((T) + 1) * 32768;                  \
            _Pragma("unroll")                                                         \
            for (int c = 0; c < 4; ++c) {                                             \
                KN[0][c] = *(const bf16x8*)(kp + c * 32);                             \
                KN[1][c] = *(const bf16x8*)(kp + 16384 + c * 32);                     \
            }                                                                         \
        }                                                                             \
        f32x4 sc0 = {0.f,0.f,0.f,0.f}, sc1 = {0.f,0.f,0.f,0.f};                       \
        _Pragma("unroll")                                                             \
        for (int c = 0; c < 4; ++c) {                                                 \
            sc0 = __builtin_amdgcn_mfma_f32_16x16x32_bf16(KC[0][c], qf[c], sc0, 0, 0, 0); \
            sc1 = __builtin_amdgcn_mfma_f32_16x16x32_bf16(KC[1][c], qf[c], sc1, 0, 0, 0); \
        }                                                                             \
        if ((T) == 31) {                                                              \
            const int sb = 992 + g * 4;                                               \
            _Pragma("unroll")                                                         \
            for (int r = 0; r < 4; ++r) {                                             \
                if (sb + r >= 1000) sc0[r] = -1e30f;                                  \
                sc1[r] = -1e30f;                                                      \
            }                                                                         \
        }                                                                             \
        float tmax = fmaxf(fmaxf(fmaxf(sc0[0], sc0[1]), fmaxf(sc0[2], sc0[3])),      \
                           fmaxf(fmaxf(sc1[0], sc1[1]), fmaxf(sc1[2], sc1[3])));      \
        tmax = fmaxf(tmax, __shfl_xor(tmax, 16));                                     \
        tmax = fmaxf(tmax, __shfl_xor(tmax, 32));                                     \
        if (!__all(tmax <= m + 8.0f)) {                                               \
            const float mnew = fmaxf(m, tmax);                                        \
            const float fsc = __builtin_amdgcn_exp2f(m - mnew);                       \
            _Pragma("unroll")                                                         \
            for (int es = 0; es < 8; ++es) acc[es] *= fsc;                            \
            lsum *= fsc;                                                              \
            m = mnew;                                                                 \
        }                                                                             \
        float p0[4], p1[4];                                                           \
        _Pragma("unroll")                                                             \
        for (int r = 0; r < 4; ++r) {                                                 \
            p0[r] = __builtin_amdgcn_exp2f(sc0[r] - m);                               \
            p1[r] = __builtin_amdgcn_exp2f(sc1[r] - m);                               \
        }                                                                             \
        bf16x8 pf;                                                                    \
        _Pragma("unroll")                                                             \
        for (int r = 0; r < 4; ++r) { pf[r] = (short)fcvt(p0[r]); pf[4+r] = (short)fcvt(p1[r]); } \
        _Pragma("unroll")                                                             \
        for (int es = 0; es < 8; ++es) {                                              \
            bf16x8 vf = { v0[es][0], v0[es][1], v0[es][2], v0[es][3],                 \
                          v1[es][0], v1[es][1], v1[es][2], v1[es][3] };               \
            acc[es] = __builtin_amdgcn_mfma_f32_16x16x32_bf16(vf, pf, acc[es], 0, 0, 0); \
        }                                                                             \
        float psum = ((p0[0] + p0[1]) + (p0[2] + p0[3]))                              \
                   + ((p1[0] + p1[1]) + (p1[2] + p1[3]));                             \
        psum += __shfl_xor(psum, 16);                                                 \
        psum += __shfl_xor(psum, 32);                                                 \
        lsum += psum;                                                                 \
    } while (0)

__global__ __launch_bounds__(256)
void attn_fwd(const unsigned short* __restrict__ Q, const unsigned short* __restrict__ K,
              const unsigned short* __restrict__ VT, unsigned short* __restrict__ O)
{
    const int h = blockIdx.y, qt = blockIdx.x;
    const int tid = threadIdx.x, l = tid & 63, w = tid >> 6;
    const int g = l >> 4, lc = l & 15;
    __shared__ unsigned short Olds[4][16][136];

    bf16x8 qf[4];
    {
        const long qrow = (long)qt * 64 + w * 16 + lc;
        const unsigned short* qp = Q + qrow * 1024 + h * 128 + g * 8;
        #pragma unroll
        for (int c = 0; c < 4; ++c) qf[c] = *(const bf16x8*)(qp + c * 32);
    }
    const unsigned short* Kp = K + h * 128 + (long)lc * 1024 + g * 8;
    const unsigned short* Vp = VT + ((long)h * 128 + lc) * 1024 + g * 4;

    float m = -1e30f, lsum = 0.f;
    f32x4 acc[8] = {};

    bf16x8 kA[2][4], kB[2][4];
    #pragma unroll
    for (int c = 0; c < 4; ++c) {
        kA[0][c] = *(const bf16x8*)(Kp + c * 32);
        kA[1][c] = *(const bf16x8*)(Kp + 16384 + c * 32);
    }

    for (int t = 0; t < 32; t += 2) {
        ATTN_TILE(t,     kA, kB);
        ATTN_TILE(t + 1, kB, kA);
    }

    const float inv = 1.f / lsum;
    #pragma unroll
    for (int es = 0; es < 8; ++es)
        #pragma unroll
        for (int r = 0; r < 4; ++r)
            Olds[w][lc][es * 16 + g * 4 + r] = fcvt(acc[es][r] * inv);
    __syncthreads();
    const long orow = (long)qt * 64 + w * 16 + (l >> 2);
    unsigned short* Op = O + (orow * 8 + h) * 128 + (l & 3) * 8;
    const unsigned short* Ol = &Olds[w][l >> 2][(l & 3) * 8];
    #pragma unroll
    for (int c2 = 0; c2 < 4; ++c2)
        *(u16x8*)(Op + c2 * 32) = *(const u16x8*)(Ol + c2 * 32);
}

// ---------------- final GEMM: C = AO @ Wo^T + bo, fp32 out -----------------
__global__ __launch_bounds__(256)
void gemm_final(const unsigned short* __restrict__ A, const unsigned short* __restrict__ B,
                const float* __restrict__ bias, float* __restrict__ C)
{
    const int tid = threadIdx.x;
    const int l = tid & 63, w = tid >> 6;
    const int wr = w >> 1, wc = w & 1;
    const int g = l >> 4, lc = l & 15;
    const long tn = (long)blockIdx.x * 128;   // 32 n-tiles (fastest: share A-tile)
    const long tm = (long)blockIdx.y * 128;   // 256 m-tiles

    bf16x8 bfv[4][4];
    #pragma unroll
    for (int n = 0; n < 4; ++n) {
        const unsigned short* bp = B + (tn + wc * 64 + n * 16 + lc) * 128 + g * 8;
        #pragma unroll
        for (int ks = 0; ks < 4; ++ks) bfv[n][ks] = *(const bf16x8*)(bp + ks * 32);
    }

    f32x4 acc[4][4] = {};
    #pragma unroll
    for (int m = 0; m < 4; ++m) {
        bf16x8 af[4];
        const unsigned short* ap = A + (tm + wr * 64 + m * 16 + lc) * 128 + g * 8;
        #pragma unroll
        for (int ks = 0; ks < 4; ++ks) af[ks] = *(const bf16x8*)(ap + ks * 32);
        #pragma unroll
        for (int n = 0; n < 4; ++n)
            #pragma unroll
            for (int ks = 0; ks < 4; ++ks)
                acc[m][n] = __builtin_amdgcn_mfma_f32_16x16x32_bf16(af[ks], bfv[n][ks], acc[m][n], 0, 0, 0);
    }

    #pragma unroll
    for (int n = 0; n < 4; ++n) {
        const long col = tn + wc * 64 + n * 16 + lc;
        const float bv = bias[col];
        #pragma unroll
        for (int m = 0; m < 4; ++m)
            #pragma unroll
            for (int r = 0; r < 4; ++r) {
                const long row = tm + wr * 64 + m * 16 + g * 4 + r;
                __builtin_nontemporal_store(acc[m][n][r] + bv, &C[row * 4096 + col]);
            }
    }
}

// ---------------- launch ----------------
// MEASUREMENT ROUND: attn_fwd launched 5x (idempotent, same inputs -> same AOb,
// deterministic across graph replays). attn_us = (dur - 394.2)/4.
extern "C" void kernel_launch(void* const* d_in, const int* in_sizes, int n_in,
                              void* d_out, int out_size, void* d_ws, size_t ws_size,
                              hipStream_t stream)
{
    const float* target = (const float*)d_in[0];
    const float* source = (const float*)d_in[1];
    const float* value  = (const float*)d_in[2];
    const float* Wq = (const float*)d_in[3];
    const float* bq = (const float*)d_in[4];
    const float* Wk = (const float*)d_in[5];
    const float* bk = (const float*)d_in[6];
    const float* Wv = (const float*)d_in[7];
    const float* bv = (const float*)d_in[8];
    const float* Wo = (const float*)d_in[9];
    const float* bo = (const float*)d_in[10];

    char* ws = (char*)d_ws;
    unsigned short* tgt_bf = (unsigned short*)(ws + 0);         // 4096x1024 bf16
    unsigned short* src_bf = (unsigned short*)(ws + 8388608);   // 1024x4096 (padded)
    unsigned short* val_bf = (unsigned short*)(ws + 16777216);  // 1024x4096 (padded)
    unsigned short* wq_bf  = (unsigned short*)(ws + 25165824);  // 1024x1024
    unsigned short* wk_bf  = (unsigned short*)(ws + 27262976);  // 1024x4096 (contig with wv)
    unsigned short* wv_bf  = (unsigned short*)(ws + 35651584);  // 1024x4096
    unsigned short* wo_bf  = (unsigned short*)(ws + 44040192);  // 4096x128
    unsigned short* Qb     = (unsigned short*)(ws + 45088768);  // 4096x1024 (exp2-domain scaled)
    unsigned short* Kb     = (unsigned short*)(ws + 53477376);  // 1024x1024
    unsigned short* VTb    = (unsigned short*)(ws + 55574528);  // 1024x1024 (V^T)
    unsigned short* AOb    = (unsigned short*)(ws + 57671680);  // 32768x128
    float* Pk = (float*)d_out;                                  // [4][1024][1024]
    float* Pv = Pk + (4L << 20);                                // [4][1024][1024]

    dim3 blk(256);
    cvt_all<<<dim3(2048, 7), blk, 0, stream>>>(
        target, tgt_bf, 4096L * 1024,
        Wq, wq_bf, 1024L * 1024,
        Wk, wk_bf, 1024L * 4096,
        Wv, wv_bf, 1024L * 4096,
        Wo, wo_bf, 4096L * 128,
        source, src_bf,
        value, val_bf);

    proj_fused<<<768, blk, 0, stream>>>(tgt_bf, wq_bf, src_bf, val_bf, wk_bf, bq, Qb, Pk, Pv);
    combine4<<<dim3(1024, 2), blk, 0, stream>>>(Pk, Pv, bk, bv, Kb, VTb);

    // 5x: instrumentation (idempotent). attn = (dur - 394.2) / 4.
    attn_fwd<<<dim3(64, 8), blk, 0, stream>>>(Qb, Kb, VTb, AOb);
    attn_fwd<<<dim3(64, 8), blk, 0, stream>>>(Qb, Kb, VTb, AOb);
    attn_fwd<<<dim3(64, 8), blk, 0, stream>>>(Qb, Kb, VTb, AOb);
    attn_fwd<<<dim3(64, 8), blk, 0, stream>>>(Qb, Kb, VTb, AOb);
    attn_fwd<<<dim3(64, 8), blk, 0, stream>>>(Qb, Kb, VTb, AOb);

    gemm_final<<<dim3(32, 256), blk, 0, stream>>>(AOb, wo_bf, bo, (float*)d_out);
}

// Round 10
// 395.837 us; speedup vs baseline: 2.7106x; 2.7106x over previous
//
#include <hip/hip_runtime.h>
#include <hip/hip_bf16.h>
#include <stdint.h>

typedef short  bf16x8 __attribute__((ext_vector_type(8)));
typedef short  bf16x4 __attribute__((ext_vector_type(4)));
typedef float  f32x4  __attribute__((ext_vector_type(4)));
typedef unsigned short u16x8 __attribute__((ext_vector_type(8)));
typedef unsigned short u16x4 __attribute__((ext_vector_type(4)));
typedef float  fx4    __attribute__((ext_vector_type(4)));

#define LDSP(p) ((__attribute__((address_space(3))) void*)(p))
#define GLBP(p) ((const __attribute__((address_space(1))) void*)(p))

__device__ __forceinline__ unsigned short f2bf(float x) {
    union { float f; unsigned u; } v; v.f = x;
    unsigned r = (v.u + 0x7FFFu + ((v.u >> 16) & 1u)) >> 16;
    return (unsigned short)r;
}
// native path: compiler emits v_cvt_pk_bf16_f32 for paired casts
__device__ __forceinline__ unsigned short fcvt(float x) {
    __hip_bfloat16 h = __float2bfloat16(x);
    return __builtin_bit_cast(unsigned short, h);
}

// ---------------- all converts in one launch: y 0-4 plain, y 5-6 row-pad ----
__global__ __launch_bounds__(256)
void cvt_all(const float* __restrict__ s0, unsigned short* __restrict__ d0, long n0,
             const float* __restrict__ s1, unsigned short* __restrict__ d1, long n1,
             const float* __restrict__ s2, unsigned short* __restrict__ d2, long n2,
             const float* __restrict__ s3, unsigned short* __restrict__ d3, long n3,
             const float* __restrict__ s4, unsigned short* __restrict__ d4, long n4,
             const float* __restrict__ s5, unsigned short* __restrict__ d5,
             const float* __restrict__ s6, unsigned short* __restrict__ d6)
{
    const int slice = blockIdx.y;
    long i = ((long)blockIdx.x * 256 + threadIdx.x) * 8;
    u16x8 o;
    if (slice < 5) {
        const float* s; unsigned short* d; long n;
        switch (slice) {
            case 0: s = s0; d = d0; n = n0; break;
            case 1: s = s1; d = d1; n = n1; break;
            case 2: s = s2; d = d2; n = n2; break;
            case 3: s = s3; d = d3; n = n3; break;
            default: s = s4; d = d4; n = n4; break;
        }
        if (i + 8 > n) return;
        fx4 a = *(const fx4*)(s + i);
        fx4 b = *(const fx4*)(s + i + 4);
        o[0]=f2bf(a[0]); o[1]=f2bf(a[1]); o[2]=f2bf(a[2]); o[3]=f2bf(a[3]);
        o[4]=f2bf(b[0]); o[5]=f2bf(b[1]); o[6]=f2bf(b[2]); o[7]=f2bf(b[3]);
        *(u16x8*)(d + i) = o;
    } else {
        const float* src = (slice == 5) ? s5 : s6;
        unsigned short* dst = (slice == 5) ? d5 : d6;
        int row = (int)(i >> 12);
        if (row < 1000) {
            long si = (long)row * 4096 + (i & 4095);
            fx4 a = *(const fx4*)(src + si);
            fx4 b = *(const fx4*)(src + si + 4);
            o[0]=f2bf(a[0]); o[1]=f2bf(a[1]); o[2]=f2bf(a[2]); o[3]=f2bf(a[3]);
            o[4]=f2bf(b[0]); o[5]=f2bf(b[1]); o[6]=f2bf(b[2]); o[7]=f2bf(b[3]);
        } else {
            #pragma unroll
            for (int j = 0; j < 8; ++j) o[j] = 0;
        }
        *(u16x8*)(dst + i) = o;
    }
}

// ---------------- fused Q + K|V projections, one 768-block launch ----------
__global__ __launch_bounds__(256)
void proj_fused(const unsigned short* __restrict__ tgt, const unsigned short* __restrict__ wq,
                const unsigned short* __restrict__ src, const unsigned short* __restrict__ val,
                const unsigned short* __restrict__ wkv,
                const float* __restrict__ bq, unsigned short* __restrict__ Qb,
                float* __restrict__ Pk, float* __restrict__ Pv)
{
    __shared__ unsigned short Alds[128 * 32];
    __shared__ unsigned short Blds[128 * 32];
    const int bid = blockIdx.x;
    const int tid = threadIdx.x;
    const int l = tid & 63, w = tid >> 6;
    const int wr = w >> 1, wc = w & 1;
    const int g = l >> 4, lc = l & 15;

    const unsigned short *A, *B;
    long tm, tn, lda;
    int kbeg;
    if (bid < 256) {
        tm = (long)(bid >> 3) * 128; tn = (long)(bid & 7) * 128;
        A = tgt; B = wq; lda = 1024; kbeg = 0;
    } else {
        const int idx = bid - 256;           // 0..511
        const int tnq = idx >> 5;            // 0..15 col tile
        const int kz  = (idx >> 3) & 3;      // 0..3
        tm = (long)(idx & 7) * 128; tn = (long)tnq * 128;
        A = (tnq < 8) ? src : val; B = wkv; lda = 4096; kbeg = kz * 1024;
    }

    f32x4 acc[4][4] = {};

    const int r0 = tid >> 2,           c0 = (tid & 3) * 8;
    const int r1 = (tid + 256) >> 2,   c1 = ((tid + 256) & 3) * 8;
    const unsigned short* a0 = A + (tm + r0) * lda + c0;
    const unsigned short* a1 = A + (tm + r1) * lda + c1;
    const unsigned short* b0 = B + (tn + r0) * lda + c0;
    const unsigned short* b1 = B + (tn + r1) * lda + c1;

    const int kend = kbeg + 1024;
    for (int k0 = kbeg; k0 < kend; k0 += 32) {
        __builtin_amdgcn_global_load_lds(GLBP(a0 + k0), LDSP(Alds + tid * 8),         16, 0, 0);
        __builtin_amdgcn_global_load_lds(GLBP(a1 + k0), LDSP(Alds + (tid + 256) * 8), 16, 0, 0);
        __builtin_amdgcn_global_load_lds(GLBP(b0 + k0), LDSP(Blds + tid * 8),         16, 0, 0);
        __builtin_amdgcn_global_load_lds(GLBP(b1 + k0), LDSP(Blds + (tid + 256) * 8), 16, 0, 0);
        __syncthreads();
        bf16x8 af[4], bfv[4];
        #pragma unroll
        for (int m = 0; m < 4; ++m)
            af[m] = *(const bf16x8*)&Alds[(wr * 64 + m * 16 + lc) * 32 + g * 8];
        #pragma unroll
        for (int n = 0; n < 4; ++n)
            bfv[n] = *(const bf16x8*)&Blds[(wc * 64 + n * 16 + lc) * 32 + g * 8];
        #pragma unroll
        for (int m = 0; m < 4; ++m)
            #pragma unroll
            for (int n = 0; n < 4; ++n)
                acc[m][n] = __builtin_amdgcn_mfma_f32_16x16x32_bf16(af[m], bfv[n], acc[m][n], 0, 0, 0);
        __syncthreads();
    }

    if (bid < 256) {
        const float qscale = 0.08838834764831845f * 1.4426950408889634f;  // 1/sqrt(128)*log2e
        #pragma unroll
        for (int n = 0; n < 4; ++n) {
            const long col = tn + wc * 64 + n * 16 + lc;
            const float bv = bq[col];
            #pragma unroll
            for (int m = 0; m < 4; ++m)
                #pragma unroll
                for (int r = 0; r < 4; ++r) {
                    const long row = tm + wr * 64 + m * 16 + g * 4 + r;
                    Qb[row * 1024 + col] = f2bf((acc[m][n][r] + bv) * qscale);
                }
        }
    } else {
        const int kz = ((bid - 256) >> 3) & 3;
        const long zoff = (long)kz << 20;
        #pragma unroll
        for (int n = 0; n < 4; ++n) {
            const long col = tn + wc * 64 + n * 16 + lc;
            #pragma unroll
            for (int m = 0; m < 4; ++m)
                #pragma unroll
                for (int r = 0; r < 4; ++r) {
                    const long row = tm + wr * 64 + m * 16 + g * 4 + r;
                    if (col < 1024) Pk[zoff + row * 1024 + col] = acc[m][n][r];
                    else            Pv[zoff + (col - 1024) * 1024 + row] = acc[m][n][r];
                }
        }
    }
}

// sum 4 split-K partials + bias -> bf16.  y=0: K [s][e] bias on col; y=1: VT [e][s] bias on row.
__global__ __launch_bounds__(256)
void combine4(const float* __restrict__ Pk, const float* __restrict__ Pv,
              const float* __restrict__ bk, const float* __restrict__ bv,
              unsigned short* __restrict__ Kb, unsigned short* __restrict__ VTb)
{
    const int half = blockIdx.y;
    const float* P = half ? Pv : Pk;
    long i = ((long)blockIdx.x * 256 + threadIdx.x) * 4;   // over 1M elems
    fx4 a = *(const fx4*)(P + i);
    fx4 b = *(const fx4*)(P + (1L << 20) + i);
    fx4 c = *(const fx4*)(P + (2L << 20) + i);
    fx4 d = *(const fx4*)(P + (3L << 20) + i);
    const int row = (int)(i >> 10), col = (int)(i & 1023);
    float bb0, bb1, bb2, bb3;
    if (half) { float x = bv[row]; bb0 = bb1 = bb2 = bb3 = x; }
    else      { bb0 = bk[col]; bb1 = bk[col + 1]; bb2 = bk[col + 2]; bb3 = bk[col + 3]; }
    u16x4 o;
    o[0] = f2bf((a[0] + b[0]) + (c[0] + d[0]) + bb0);
    o[1] = f2bf((a[1] + b[1]) + (c[1] + d[1]) + bb1);
    o[2] = f2bf((a[2] + b[2]) + (c[2] + d[2]) + bb2);
    o[3] = f2bf((a[3] + b[3]) + (c[3] + d[3]) + bb3);
    *(u16x4*)((half ? VTb : Kb) + i) = o;
}

// ---------------- S-split flash attention ----------------------------------
// Each block owns 16 q-rows of one head; its 4 waves each process 8 of the
// 32 k-tiles (serial chain 32 -> 8), then merge online-softmax states in LDS.
// Grid 256x8 = 2048 blocks (4x r8) -> ~16 waves/CU (8x today's concurrency).
// __launch_bounds__(256,4) caps VGPR at 128 so 4 blocks/CU fit.
__global__ __launch_bounds__(256, 4)
void attn_fwd(const unsigned short* __restrict__ Q, const unsigned short* __restrict__ K,
              const unsigned short* __restrict__ VT, unsigned short* __restrict__ O)
{
    const int h = blockIdx.y, qt = blockIdx.x;       // 16 q-rows per block
    const int tid = threadIdx.x, l = tid & 63, w = tid >> 6;
    const int g = l >> 4, lc = l & 15;

    __shared__ float accL[4][64][33];                // +1 pad: conflict-free
    __shared__ float mL[4][64];
    __shared__ float lL[4][64];
    __shared__ unsigned short Olds[16][136];

    bf16x8 qf[4];
    {
        const long qrow = (long)qt * 16 + lc;
        const unsigned short* qp = Q + qrow * 1024 + h * 128 + g * 8;
        #pragma unroll
        for (int c = 0; c < 4; ++c) qf[c] = *(const bf16x8*)(qp + c * 32);
    }
    const unsigned short* Kp = K + h * 128 + (long)lc * 1024 + g * 8;
    const unsigned short* Vp = VT + ((long)h * 128 + lc) * 1024 + g * 4;

    float m = -1e30f, lsum = 0.f;
    f32x4 acc[8] = {};

    const int t0 = w * 8;                            // this wave's k-chunk
    for (int ti = 0; ti < 8; ++ti) {
        const int t = t0 + ti;
        bf16x4 v0[8], v1[8];
        #pragma unroll
        for (int es = 0; es < 8; ++es) {
            const unsigned short* vp = Vp + (long)es * 16384 + t * 32;
            v0[es] = *(const bf16x4*)vp;
            v1[es] = *(const bf16x4*)(vp + 16);
        }
        const unsigned short* kp = Kp + (long)t * 32768;
        f32x4 sc0 = {0.f,0.f,0.f,0.f}, sc1 = {0.f,0.f,0.f,0.f};
        #pragma unroll
        for (int c = 0; c < 4; ++c) {
            bf16x8 kf0 = *(const bf16x8*)(kp + c * 32);
            bf16x8 kf1 = *(const bf16x8*)(kp + 16384 + c * 32);
            sc0 = __builtin_amdgcn_mfma_f32_16x16x32_bf16(kf0, qf[c], sc0, 0, 0, 0);
            sc1 = __builtin_amdgcn_mfma_f32_16x16x32_bf16(kf1, qf[c], sc1, 0, 0, 0);
        }
        if (t == 31) {                               // wave 3 only, uniform
            const int sb = 992 + g * 4;
            #pragma unroll
            for (int r = 0; r < 4; ++r) {
                if (sb + r >= 1000) sc0[r] = -1e30f;
                sc1[r] = -1e30f;
            }
        }
        float tmax = fmaxf(fmaxf(fmaxf(sc0[0], sc0[1]), fmaxf(sc0[2], sc0[3])),
                           fmaxf(fmaxf(sc1[0], sc1[1]), fmaxf(sc1[2], sc1[3])));
        tmax = fmaxf(tmax, __shfl_xor(tmax, 16));
        tmax = fmaxf(tmax, __shfl_xor(tmax, 32));
        if (!__all(tmax <= m + 8.0f)) {              // T13 defer-max
            const float mnew = fmaxf(m, tmax);
            const float fsc = __builtin_amdgcn_exp2f(m - mnew);
            #pragma unroll
            for (int es = 0; es < 8; ++es) acc[es] *= fsc;
            lsum *= fsc;
            m = mnew;
        }
        float p0[4], p1[4];
        #pragma unroll
        for (int r = 0; r < 4; ++r) {
            p0[r] = __builtin_amdgcn_exp2f(sc0[r] - m);
            p1[r] = __builtin_amdgcn_exp2f(sc1[r] - m);
        }
        bf16x8 pf;   // slot j: P^T[sigma(g,j)][q], sigma matches V-frag slots
        #pragma unroll
        for (int r = 0; r < 4; ++r) { pf[r] = (short)fcvt(p0[r]); pf[4 + r] = (short)fcvt(p1[r]); }
        #pragma unroll
        for (int es = 0; es < 8; ++es) {
            bf16x8 vf = { v0[es][0], v0[es][1], v0[es][2], v0[es][3],
                          v1[es][0], v1[es][1], v1[es][2], v1[es][3] };
            acc[es] = __builtin_amdgcn_mfma_f32_16x16x32_bf16(vf, pf, acc[es], 0, 0, 0);
        }
        float psum = ((p0[0] + p0[1]) + (p0[2] + p0[3]))
                   + ((p1[0] + p1[1]) + (p1[2] + p1[3]));
        psum += __shfl_xor(psum, 16);
        psum += __shfl_xor(psum, 32);
        lsum += psum;
    }

    // ---- cross-wave online-softmax merge ----
    mL[w][l] = m;
    lL[w][l] = lsum;
    #pragma unroll
    for (int es = 0; es < 8; ++es)
        #pragma unroll
        for (int r = 0; r < 4; ++r)
            accL[w][l][es * 4 + r] = acc[es][r];
    __syncthreads();

    if (w == 0) {
        const float m0 = mL[0][l], m1 = mL[1][l], m2 = mL[2][l], m3 = mL[3][l];
        const float mm = fmaxf(fmaxf(m0, m1), fmaxf(m2, m3));
        const float f0 = __builtin_amdgcn_exp2f(m0 - mm);
        const float f1 = __builtin_amdgcn_exp2f(m1 - mm);
        const float f2 = __builtin_amdgcn_exp2f(m2 - mm);
        const float f3 = __builtin_amdgcn_exp2f(m3 - mm);
        const float lt = f0 * lL[0][l] + f1 * lL[1][l] + f2 * lL[2][l] + f3 * lL[3][l];
        const float inv = 1.f / lt;
        #pragma unroll
        for (int j = 0; j < 32; ++j) {
            const float a = f0 * accL[0][l][j] + f1 * accL[1][l][j]
                          + f2 * accL[2][l][j] + f3 * accL[3][l][j];
            Olds[lc][(j >> 2) * 16 + g * 4 + (j & 3)] = fcvt(a * inv);
        }
        const long orow = (long)qt * 16 + (l >> 2);
        unsigned short* Op = O + (orow * 8 + h) * 128 + (l & 3) * 8;
        const unsigned short* Ol = &Olds[l >> 2][(l & 3) * 8];
        #pragma unroll
        for (int c2 = 0; c2 < 4; ++c2)
            *(u16x8*)(Op + c2 * 32) = *(const u16x8*)(Ol + c2 * 32);
    }
}

// ---------------- final GEMM: C = AO @ Wo^T + bo, fp32 out -----------------
__global__ __launch_bounds__(256)
void gemm_final(const unsigned short* __restrict__ A, const unsigned short* __restrict__ B,
                const float* __restrict__ bias, float* __restrict__ C)
{
    const int tid = threadIdx.x;
    const int l = tid & 63, w = tid >> 6;
    const int wr = w >> 1, wc = w & 1;
    const int g = l >> 4, lc = l & 15;
    const long tn = (long)blockIdx.x * 128;   // 32 n-tiles (fastest: share A-tile)
    const long tm = (long)blockIdx.y * 128;   // 256 m-tiles

    bf16x8 bfv[4][4];
    #pragma unroll
    for (int n = 0; n < 4; ++n) {
        const unsigned short* bp = B + (tn + wc * 64 + n * 16 + lc) * 128 + g * 8;
        #pragma unroll
        for (int ks = 0; ks < 4; ++ks) bfv[n][ks] = *(const bf16x8*)(bp + ks * 32);
    }

    f32x4 acc[4][4] = {};
    #pragma unroll
    for (int m = 0; m < 4; ++m) {
        bf16x8 af[4];
        const unsigned short* ap = A + (tm + wr * 64 + m * 16 + lc) * 128 + g * 8;
        #pragma unroll
        for (int ks = 0; ks < 4; ++ks) af[ks] = *(const bf16x8*)(ap + ks * 32);
        #pragma unroll
        for (int n = 0; n < 4; ++n)
            #pragma unroll
            for (int ks = 0; ks < 4; ++ks)
                acc[m][n] = __builtin_amdgcn_mfma_f32_16x16x32_bf16(af[ks], bfv[n][ks], acc[m][n], 0, 0, 0);
    }

    #pragma unroll
    for (int n = 0; n < 4; ++n) {
        const long col = tn + wc * 64 + n * 16 + lc;
        const float bv = bias[col];
        #pragma unroll
        for (int m = 0; m < 4; ++m)
            #pragma unroll
            for (int r = 0; r < 4; ++r) {
                const long row = tm + wr * 64 + m * 16 + g * 4 + r;
                __builtin_nontemporal_store(acc[m][n][r] + bv, &C[row * 4096 + col]);
            }
    }
}

// ---------------- launch ----------------
extern "C" void kernel_launch(void* const* d_in, const int* in_sizes, int n_in,
                              void* d_out, int out_size, void* d_ws, size_t ws_size,
                              hipStream_t stream)
{
    const float* target = (const float*)d_in[0];
    const float* source = (const float*)d_in[1];
    const float* value  = (const float*)d_in[2];
    const float* Wq = (const float*)d_in[3];
    const float* bq = (const float*)d_in[4];
    const float* Wk = (const float*)d_in[5];
    const float* bk = (const float*)d_in[6];
    const float* Wv = (const float*)d_in[7];
    const float* bv = (const float*)d_in[8];
    const float* Wo = (const float*)d_in[9];
    const float* bo = (const float*)d_in[10];

    char* ws = (char*)d_ws;
    unsigned short* tgt_bf = (unsigned short*)(ws + 0);         // 4096x1024 bf16
    unsigned short* src_bf = (unsigned short*)(ws + 8388608);   // 1024x4096 (padded)
    unsigned short* val_bf = (unsigned short*)(ws + 16777216);  // 1024x4096 (padded)
    unsigned short* wq_bf  = (unsigned short*)(ws + 25165824);  // 1024x1024
    unsigned short* wk_bf  = (unsigned short*)(ws + 27262976);  // 1024x4096 (contig with wv)
    unsigned short* wv_bf  = (unsigned short*)(ws + 35651584);  // 1024x4096
    unsigned short* wo_bf  = (unsigned short*)(ws + 44040192);  // 4096x128
    unsigned short* Qb     = (unsigned short*)(ws + 45088768);  // 4096x1024 (exp2-domain scaled)
    unsigned short* Kb     = (unsigned short*)(ws + 53477376);  // 1024x1024
    unsigned short* VTb    = (unsigned short*)(ws + 55574528);  // 1024x1024 (V^T)
    unsigned short* AOb    = (unsigned short*)(ws + 57671680);  // 32768x128
    float* Pk = (float*)d_out;                                  // [4][1024][1024]
    float* Pv = Pk + (4L << 20);                                // [4][1024][1024]

    dim3 blk(256);
    cvt_all<<<dim3(2048, 7), blk, 0, stream>>>(
        target, tgt_bf, 4096L * 1024,
        Wq, wq_bf, 1024L * 1024,
        Wk, wk_bf, 1024L * 4096,
        Wv, wv_bf, 1024L * 4096,
        Wo, wo_bf, 4096L * 128,
        source, src_bf,
        value, val_bf);

    proj_fused<<<768, blk, 0, stream>>>(tgt_bf, wq_bf, src_bf, val_bf, wk_bf, bq, Qb, Pk, Pv);
    combine4<<<dim3(1024, 2), blk, 0, stream>>>(Pk, Pv, bk, bv, Kb, VTb);

    attn_fwd<<<dim3(256, 8), blk, 0, stream>>>(Qb, Kb, VTb, AOb);

    gemm_final<<<dim3(32, 256), blk, 0, stream>>>(AOb, wo_bf, bo, (float*)d_out);
}

// Round 11
// 262.902 us; speedup vs baseline: 4.0812x; 1.5056x over previous
//
#include <hip/hip_runtime.h>
#include <hip/hip_bf16.h>
#include <stdint.h>

typedef short  bf16x8 __attribute__((ext_vector_type(8)));
typedef short  bf16x4 __attribute__((ext_vector_type(4)));
typedef float  f32x4  __attribute__((ext_vector_type(4)));
typedef unsigned short u16x8 __attribute__((ext_vector_type(8)));
typedef unsigned short u16x4 __attribute__((ext_vector_type(4)));
typedef float  fx4    __attribute__((ext_vector_type(4)));

#define LDSP(p) ((__attribute__((address_space(3))) void*)(p))
#define GLBP(p) ((const __attribute__((address_space(1))) void*)(p))

__device__ __forceinline__ unsigned short f2bf(float x) {
    union { float f; unsigned u; } v; v.f = x;
    unsigned r = (v.u + 0x7FFFu + ((v.u >> 16) & 1u)) >> 16;
    return (unsigned short)r;
}
// native path: compiler emits v_cvt_pk_bf16_f32 for paired casts
__device__ __forceinline__ unsigned short fcvt(float x) {
    __hip_bfloat16 h = __float2bfloat16(x);
    return __builtin_bit_cast(unsigned short, h);
}

// ---------------- all converts in one launch: y 0-4 plain, y 5-6 row-pad ----
__global__ __launch_bounds__(256)
void cvt_all(const float* __restrict__ s0, unsigned short* __restrict__ d0, long n0,
             const float* __restrict__ s1, unsigned short* __restrict__ d1, long n1,
             const float* __restrict__ s2, unsigned short* __restrict__ d2, long n2,
             const float* __restrict__ s3, unsigned short* __restrict__ d3, long n3,
             const float* __restrict__ s4, unsigned short* __restrict__ d4, long n4,
             const float* __restrict__ s5, unsigned short* __restrict__ d5,
             const float* __restrict__ s6, unsigned short* __restrict__ d6)
{
    const int slice = blockIdx.y;
    long i = ((long)blockIdx.x * 256 + threadIdx.x) * 8;
    u16x8 o;
    if (slice < 5) {
        const float* s; unsigned short* d; long n;
        switch (slice) {
            case 0: s = s0; d = d0; n = n0; break;
            case 1: s = s1; d = d1; n = n1; break;
            case 2: s = s2; d = d2; n = n2; break;
            case 3: s = s3; d = d3; n = n3; break;
            default: s = s4; d = d4; n = n4; break;
        }
        if (i + 8 > n) return;
        fx4 a = *(const fx4*)(s + i);
        fx4 b = *(const fx4*)(s + i + 4);
        o[0]=f2bf(a[0]); o[1]=f2bf(a[1]); o[2]=f2bf(a[2]); o[3]=f2bf(a[3]);
        o[4]=f2bf(b[0]); o[5]=f2bf(b[1]); o[6]=f2bf(b[2]); o[7]=f2bf(b[3]);
        *(u16x8*)(d + i) = o;
    } else {
        const float* src = (slice == 5) ? s5 : s6;
        unsigned short* dst = (slice == 5) ? d5 : d6;
        int row = (int)(i >> 12);
        if (row < 1000) {
            long si = (long)row * 4096 + (i & 4095);
            fx4 a = *(const fx4*)(src + si);
            fx4 b = *(const fx4*)(src + si + 4);
            o[0]=f2bf(a[0]); o[1]=f2bf(a[1]); o[2]=f2bf(a[2]); o[3]=f2bf(a[3]);
            o[4]=f2bf(b[0]); o[5]=f2bf(b[1]); o[6]=f2bf(b[2]); o[7]=f2bf(b[3]);
        } else {
            #pragma unroll
            for (int j = 0; j < 8; ++j) o[j] = 0;
        }
        *(u16x8*)(dst + i) = o;
    }
}

// ---------------- fused Q + K|V projections, one 768-block launch ----------
__global__ __launch_bounds__(256)
void proj_fused(const unsigned short* __restrict__ tgt, const unsigned short* __restrict__ wq,
                const unsigned short* __restrict__ src, const unsigned short* __restrict__ val,
                const unsigned short* __restrict__ wkv,
                const float* __restrict__ bq, unsigned short* __restrict__ Qb,
                float* __restrict__ Pk, float* __restrict__ Pv)
{
    __shared__ unsigned short Alds[128 * 32];
    __shared__ unsigned short Blds[128 * 32];
    const int bid = blockIdx.x;
    const int tid = threadIdx.x;
    const int l = tid & 63, w = tid >> 6;
    const int wr = w >> 1, wc = w & 1;
    const int g = l >> 4, lc = l & 15;

    const unsigned short *A, *B;
    long tm, tn, lda;
    int kbeg;
    if (bid < 256) {
        tm = (long)(bid >> 3) * 128; tn = (long)(bid & 7) * 128;
        A = tgt; B = wq; lda = 1024; kbeg = 0;
    } else {
        const int idx = bid - 256;           // 0..511
        const int tnq = idx >> 5;            // 0..15 col tile
        const int kz  = (idx >> 3) & 3;      // 0..3
        tm = (long)(idx & 7) * 128; tn = (long)tnq * 128;
        A = (tnq < 8) ? src : val; B = wkv; lda = 4096; kbeg = kz * 1024;
    }

    f32x4 acc[4][4] = {};

    const int r0 = tid >> 2,           c0 = (tid & 3) * 8;
    const int r1 = (tid + 256) >> 2,   c1 = ((tid + 256) & 3) * 8;
    const unsigned short* a0 = A + (tm + r0) * lda + c0;
    const unsigned short* a1 = A + (tm + r1) * lda + c1;
    const unsigned short* b0 = B + (tn + r0) * lda + c0;
    const unsigned short* b1 = B + (tn + r1) * lda + c1;

    const int kend = kbeg + 1024;
    for (int k0 = kbeg; k0 < kend; k0 += 32) {
        __builtin_amdgcn_global_load_lds(GLBP(a0 + k0), LDSP(Alds + tid * 8),         16, 0, 0);
        __builtin_amdgcn_global_load_lds(GLBP(a1 + k0), LDSP(Alds + (tid + 256) * 8), 16, 0, 0);
        __builtin_amdgcn_global_load_lds(GLBP(b0 + k0), LDSP(Blds + tid * 8),         16, 0, 0);
        __builtin_amdgcn_global_load_lds(GLBP(b1 + k0), LDSP(Blds + (tid + 256) * 8), 16, 0, 0);
        __syncthreads();
        bf16x8 af[4], bfv[4];
        #pragma unroll
        for (int m = 0; m < 4; ++m)
            af[m] = *(const bf16x8*)&Alds[(wr * 64 + m * 16 + lc) * 32 + g * 8];
        #pragma unroll
        for (int n = 0; n < 4; ++n)
            bfv[n] = *(const bf16x8*)&Blds[(wc * 64 + n * 16 + lc) * 32 + g * 8];
        #pragma unroll
        for (int m = 0; m < 4; ++m)
            #pragma unroll
            for (int n = 0; n < 4; ++n)
                acc[m][n] = __builtin_amdgcn_mfma_f32_16x16x32_bf16(af[m], bfv[n], acc[m][n], 0, 0, 0);
        __syncthreads();
    }

    if (bid < 256) {
        const float qscale = 0.08838834764831845f * 1.4426950408889634f;  // 1/sqrt(128)*log2e
        #pragma unroll
        for (int n = 0; n < 4; ++n) {
            const long col = tn + wc * 64 + n * 16 + lc;
            const float bv = bq[col];
            #pragma unroll
            for (int m = 0; m < 4; ++m)
                #pragma unroll
                for (int r = 0; r < 4; ++r) {
                    const long row = tm + wr * 64 + m * 16 + g * 4 + r;
                    Qb[row * 1024 + col] = f2bf((acc[m][n][r] + bv) * qscale);
                }
        }
    } else {
        const int kz = ((bid - 256) >> 3) & 3;
        const long zoff = (long)kz << 20;
        #pragma unroll
        for (int n = 0; n < 4; ++n) {
            const long col = tn + wc * 64 + n * 16 + lc;
            #pragma unroll
            for (int m = 0; m < 4; ++m)
                #pragma unroll
                for (int r = 0; r < 4; ++r) {
                    const long row = tm + wr * 64 + m * 16 + g * 4 + r;
                    if (col < 1024) Pk[zoff + row * 1024 + col] = acc[m][n][r];
                    else            Pv[zoff + (col - 1024) * 1024 + row] = acc[m][n][r];
                }
        }
    }
}

// sum 4 split-K partials + bias -> bf16.  y=0: K [s][e] bias on col; y=1: VT [e][s] bias on row.
__global__ __launch_bounds__(256)
void combine4(const float* __restrict__ Pk, const float* __restrict__ Pv,
              const float* __restrict__ bk, const float* __restrict__ bv,
              unsigned short* __restrict__ Kb, unsigned short* __restrict__ VTb)
{
    const int half = blockIdx.y;
    const float* P = half ? Pv : Pk;
    long i = ((long)blockIdx.x * 256 + threadIdx.x) * 4;   // over 1M elems
    fx4 a = *(const fx4*)(P + i);
    fx4 b = *(const fx4*)(P + (1L << 20) + i);
    fx4 c = *(const fx4*)(P + (2L << 20) + i);
    fx4 d = *(const fx4*)(P + (3L << 20) + i);
    const int row = (int)(i >> 10), col = (int)(i & 1023);
    float bb0, bb1, bb2, bb3;
    if (half) { float x = bv[row]; bb0 = bb1 = bb2 = bb3 = x; }
    else      { bb0 = bk[col]; bb1 = bk[col + 1]; bb2 = bk[col + 2]; bb3 = bk[col + 3]; }
    u16x4 o;
    o[0] = f2bf((a[0] + b[0]) + (c[0] + d[0]) + bb0);
    o[1] = f2bf((a[1] + b[1]) + (c[1] + d[1]) + bb1);
    o[2] = f2bf((a[2] + b[2]) + (c[2] + d[2]) + bb2);
    o[3] = f2bf((a[3] + b[3]) + (c[3] + d[3]) + bb3);
    *(u16x4*)((half ? VTb : Kb) + i) = o;
}

// ---------------- flash attention with LDS-staged K/V tiles ----------------
// Theory (r7-r10 counters): direct per-lane fragment loads are TA/L1-bound
// (each instr touches ~16 lines; 384 line-reqs/wave-tile). Fix: stage K
// (32x128) and V^T (128x32) tiles in LDS once per block (coalesced reg-staged
// loads, 4 instrs/wave), double-buffered, ONE barrier per tile; fragments
// come from LDS. Bank-balanced layouts: K [32][136] (272B stride -> b128
// reads perfectly 8/bank), V [128][40] (80B stride -> b64 reads 4/bank).
// Olds aliases the K buffers after the final barrier.
__global__ __launch_bounds__(256, 3)
void attn_fwd(const unsigned short* __restrict__ Q, const unsigned short* __restrict__ K,
              const unsigned short* __restrict__ VT, unsigned short* __restrict__ O)
{
    const int h = blockIdx.y, qt = blockIdx.x;
    const int tid = threadIdx.x, l = tid & 63, w = tid >> 6;
    const int g = l >> 4, lc = l & 15;

    __shared__ unsigned short smem[18944];       // 37.9 KB
    unsigned short* const Kl0 = smem;            // [32][136]
    unsigned short* const Kl1 = smem + 4352;
    unsigned short* const Vl0 = smem + 8704;     // [128][40]
    unsigned short* const Vl1 = smem + 13824;

    bf16x8 qf[4];
    {
        const long qrow = (long)qt * 64 + w * 16 + lc;
        const unsigned short* qp = Q + qrow * 1024 + h * 128 + g * 8;
        #pragma unroll
        for (int c = 0; c < 4; ++c) qf[c] = *(const bf16x8*)(qp + c * 32);
    }

    // staging geometry: K chunk (row=tid>>4 [+16], col8=(tid&15)*8);
    //                   V chunk (e=tid>>2 [+64], col=(tid&3)*8)
    const int krow = tid >> 4;
    const int kcol = (tid & 15) * 8;
    const int ve   = tid >> 2;
    const int vcol = (tid & 3) * 8;
    const unsigned short* Kg = K + h * 128;
    const unsigned short* Vg = VT + (long)h * 128 * 1024;

    u16x8 kg0, kg1, vg0, vg1;
#define LOADG(T) do {                                                        \
        kg0 = *(const u16x8*)(Kg + (long)((T) * 32 + krow) * 1024 + kcol);    \
        kg1 = *(const u16x8*)(Kg + (long)((T) * 32 + krow + 16) * 1024 + kcol);\
        vg0 = *(const u16x8*)(Vg + (long)ve * 1024 + (T) * 32 + vcol);        \
        vg1 = *(const u16x8*)(Vg + (long)(ve + 64) * 1024 + (T) * 32 + vcol); \
    } while (0)
#define WRITEL(KB, VB) do {                                                  \
        *(u16x8*)((KB) + krow * 136 + kcol) = kg0;                            \
        *(u16x8*)((KB) + (krow + 16) * 136 + kcol) = kg1;                     \
        *(u16x8*)((VB) + ve * 40 + vcol) = vg0;                               \
        *(u16x8*)((VB) + (ve + 64) * 40 + vcol) = vg1;                        \
    } while (0)

    float m = -1e30f, lsum = 0.f;
    f32x4 acc[8] = {};

    LOADG(0);
    WRITEL(Kl0, Vl0);
    __syncthreads();

    for (int t = 0; t < 32; ++t) {
        if (t < 31) LOADG(t + 1);                 // issue early; hides under compute
        const unsigned short* Kb = (t & 1) ? Kl1 : Kl0;
        const unsigned short* Vb = (t & 1) ? Vl1 : Vl0;

        f32x4 sc0 = {0.f,0.f,0.f,0.f}, sc1 = {0.f,0.f,0.f,0.f};
        #pragma unroll
        for (int c = 0; c < 4; ++c) {
            bf16x8 kf0 = *(const bf16x8*)(Kb + lc * 136 + g * 8 + c * 32);
            bf16x8 kf1 = *(const bf16x8*)(Kb + (16 + lc) * 136 + g * 8 + c * 32);
            sc0 = __builtin_amdgcn_mfma_f32_16x16x32_bf16(kf0, qf[c], sc0, 0, 0, 0);
            sc1 = __builtin_amdgcn_mfma_f32_16x16x32_bf16(kf1, qf[c], sc1, 0, 0, 0);
        }
        if (t == 31) {                            // only tile with s >= 1000
            const int sb = 992 + g * 4;
            #pragma unroll
            for (int r = 0; r < 4; ++r) {
                if (sb + r >= 1000) sc0[r] = -1e30f;
                sc1[r] = -1e30f;
            }
        }
        float tmax = fmaxf(fmaxf(fmaxf(sc0[0], sc0[1]), fmaxf(sc0[2], sc0[3])),
                           fmaxf(fmaxf(sc1[0], sc1[1]), fmaxf(sc1[2], sc1[3])));
        tmax = fmaxf(tmax, __shfl_xor(tmax, 16));
        tmax = fmaxf(tmax, __shfl_xor(tmax, 32));
        if (!__all(tmax <= m + 8.0f)) {           // T13 defer-max
            const float mnew = fmaxf(m, tmax);
            const float fsc = __builtin_amdgcn_exp2f(m - mnew);
            #pragma unroll
            for (int es = 0; es < 8; ++es) acc[es] *= fsc;
            lsum *= fsc;
            m = mnew;
        }
        float p0[4], p1[4];
        #pragma unroll
        for (int r = 0; r < 4; ++r) {
            p0[r] = __builtin_amdgcn_exp2f(sc0[r] - m);
            p1[r] = __builtin_amdgcn_exp2f(sc1[r] - m);
        }
        bf16x8 pf;   // slot j: P^T[sigma(g,j)][q], sigma matches V-frag slots
        #pragma unroll
        for (int r = 0; r < 4; ++r) { pf[r] = (short)fcvt(p0[r]); pf[4 + r] = (short)fcvt(p1[r]); }
        #pragma unroll
        for (int es = 0; es < 8; ++es) {
            const unsigned short* vp = Vb + (es * 16 + lc) * 40 + g * 4;
            bf16x4 v0 = *(const bf16x4*)vp;
            bf16x4 v1 = *(const bf16x4*)(vp + 16);
            bf16x8 vf = { v0[0], v0[1], v0[2], v0[3], v1[0], v1[1], v1[2], v1[3] };
            acc[es] = __builtin_amdgcn_mfma_f32_16x16x32_bf16(vf, pf, acc[es], 0, 0, 0);
        }
        float psum = ((p0[0] + p0[1]) + (p0[2] + p0[3]))
                   + ((p1[0] + p1[1]) + (p1[2] + p1[3]));
        psum += __shfl_xor(psum, 16);
        psum += __shfl_xor(psum, 32);
        lsum += psum;

        if (t < 31) WRITEL((t & 1) ? Kl0 : Kl1, (t & 1) ? Vl0 : Vl1);
        __syncthreads();                          // one barrier per tile
    }
#undef LOADG
#undef WRITEL

    // epilogue: O^T/lsum -> LDS transpose (aliases K buffers) -> coalesced rows
    unsigned short* const Olds = smem;            // [4][16][136], 8704 elems
    const float inv = 1.f / lsum;
    #pragma unroll
    for (int es = 0; es < 8; ++es)
        #pragma unroll
        for (int r = 0; r < 4; ++r)
            Olds[w * 2176 + lc * 136 + es * 16 + g * 4 + r] = fcvt(acc[es][r] * inv);
    __syncthreads();
    const long orow = (long)qt * 64 + w * 16 + (l >> 2);
    unsigned short* Op = O + (orow * 8 + h) * 128 + (l & 3) * 8;
    const unsigned short* Ol = Olds + w * 2176 + (l >> 2) * 136 + (l & 3) * 8;
    #pragma unroll
    for (int c2 = 0; c2 < 4; ++c2)
        *(u16x8*)(Op + c2 * 32) = *(const u16x8*)(Ol + c2 * 32);
}

// ---------------- final GEMM: C = AO @ Wo^T + bo, fp32 out -----------------
__global__ __launch_bounds__(256)
void gemm_final(const unsigned short* __restrict__ A, const unsigned short* __restrict__ B,
                const float* __restrict__ bias, float* __restrict__ C)
{
    const int tid = threadIdx.x;
    const int l = tid & 63, w = tid >> 6;
    const int wr = w >> 1, wc = w & 1;
    const int g = l >> 4, lc = l & 15;
    const long tn = (long)blockIdx.x * 128;   // 32 n-tiles (fastest: share A-tile)
    const long tm = (long)blockIdx.y * 128;   // 256 m-tiles

    bf16x8 bfv[4][4];
    #pragma unroll
    for (int n = 0; n < 4; ++n) {
        const unsigned short* bp = B + (tn + wc * 64 + n * 16 + lc) * 128 + g * 8;
        #pragma unroll
        for (int ks = 0; ks < 4; ++ks) bfv[n][ks] = *(const bf16x8*)(bp + ks * 32);
    }

    f32x4 acc[4][4] = {};
    #pragma unroll
    for (int m = 0; m < 4; ++m) {
        bf16x8 af[4];
        const unsigned short* ap = A + (tm + wr * 64 + m * 16 + lc) * 128 + g * 8;
        #pragma unroll
        for (int ks = 0; ks < 4; ++ks) af[ks] = *(const bf16x8*)(ap + ks * 32);
        #pragma unroll
        for (int n = 0; n < 4; ++n)
            #pragma unroll
            for (int ks = 0; ks < 4; ++ks)
                acc[m][n] = __builtin_amdgcn_mfma_f32_16x16x32_bf16(af[ks], bfv[n][ks], acc[m][n], 0, 0, 0);
    }

    #pragma unroll
    for (int n = 0; n < 4; ++n) {
        const long col = tn + wc * 64 + n * 16 + lc;
        const float bv = bias[col];
        #pragma unroll
        for (int m = 0; m < 4; ++m)
            #pragma unroll
            for (int r = 0; r < 4; ++r) {
                const long row = tm + wr * 64 + m * 16 + g * 4 + r;
                __builtin_nontemporal_store(acc[m][n][r] + bv, &C[row * 4096 + col]);
            }
    }
}

// ---------------- launch ----------------
extern "C" void kernel_launch(void* const* d_in, const int* in_sizes, int n_in,
                              void* d_out, int out_size, void* d_ws, size_t ws_size,
                              hipStream_t stream)
{
    const float* target = (const float*)d_in[0];
    const float* source = (const float*)d_in[1];
    const float* value  = (const float*)d_in[2];
    const float* Wq = (const float*)d_in[3];
    const float* bq = (const float*)d_in[4];
    const float* Wk = (const float*)d_in[5];
    const float* bk = (const float*)d_in[6];
    const float* Wv = (const float*)d_in[7];
    const float* bv = (const float*)d_in[8];
    const float* Wo = (const float*)d_in[9];
    const float* bo = (const float*)d_in[10];

    char* ws = (char*)d_ws;
    unsigned short* tgt_bf = (unsigned short*)(ws + 0);         // 4096x1024 bf16
    unsigned short* src_bf = (unsigned short*)(ws + 8388608);   // 1024x4096 (padded)
    unsigned short* val_bf = (unsigned short*)(ws + 16777216);  // 1024x4096 (padded)
    unsigned short* wq_bf  = (unsigned short*)(ws + 25165824);  // 1024x1024
    unsigned short* wk_bf  = (unsigned short*)(ws + 27262976);  // 1024x4096 (contig with wv)
    unsigned short* wv_bf  = (unsigned short*)(ws + 35651584);  // 1024x4096
    unsigned short* wo_bf  = (unsigned short*)(ws + 44040192);  // 4096x128
    unsigned short* Qb     = (unsigned short*)(ws + 45088768);  // 4096x1024 (exp2-domain scaled)
    unsigned short* Kb     = (unsigned short*)(ws + 53477376);  // 1024x1024
    unsigned short* VTb    = (unsigned short*)(ws + 55574528);  // 1024x1024 (V^T)
    unsigned short* AOb    = (unsigned short*)(ws + 57671680);  // 32768x128
    float* Pk = (float*)d_out;                                  // [4][1024][1024]
    float* Pv = Pk + (4L << 20);                                // [4][1024][1024]

    dim3 blk(256);
    cvt_all<<<dim3(2048, 7), blk, 0, stream>>>(
        target, tgt_bf, 4096L * 1024,
        Wq, wq_bf, 1024L * 1024,
        Wk, wk_bf, 1024L * 4096,
        Wv, wv_bf, 1024L * 4096,
        Wo, wo_bf, 4096L * 128,
        source, src_bf,
        value, val_bf);

    proj_fused<<<768, blk, 0, stream>>>(tgt_bf, wq_bf, src_bf, val_bf, wk_bf, bq, Qb, Pk, Pv);
    combine4<<<dim3(1024, 2), blk, 0, stream>>>(Pk, Pv, bk, bv, Kb, VTb);

    attn_fwd<<<dim3(64, 8), blk, 0, stream>>>(Qb, Kb, VTb, AOb);

    gemm_final<<<dim3(32, 256), blk, 0, stream>>>(AOb, wo_bf, bo, (float*)d_out);
}